// Round 14
// baseline (92.018 us; speedup 1.0000x reference)
//
#include <hip/hip_runtime.h>
#include <hip/hip_fp16.h>

#define IN_CH 32
#define OUT_CH 128
#define BSHIFT 7
#define BW 128          // nodes per bucket
#define NB_P 1024       // >= ceil(100000/128)=782
#define PCHUNK 4096     // edges per partition block (512 thr x 8)
#define ACH 4096        // edges per k_agg sort-chunk (== slab cap: single pass)

// ---------------------------------------------------------------------------
// H: fp32 -> fp16 copy of x (round-to-nearest). Halves gather bytes/row.
// ---------------------------------------------------------------------------
__global__ __launch_bounds__(512) void k_half(const float* __restrict__ x,
                                              __half* __restrict__ xh,
                                              int total4) {   // n*IN_CH/4
  int i = blockIdx.x * 512 + threadIdx.x;
  if (i < total4) {
    float4 v = reinterpret_cast<const float4*>(x)[i];
    __half2 a = __floats2half2_rn(v.x, v.y);
    __half2 b = __floats2half2_rn(v.z, v.w);
    uint2 o;
    o.x = *reinterpret_cast<unsigned*>(&a);
    o.y = *reinterpret_cast<unsigned*>(&b);
    reinterpret_cast<uint2*>(xh)[i] = o;
  }
}

// ---------------------------------------------------------------------------
// C: partition with LDS reorder (R13-proven: 512 thr / 4096-edge chunks,
//    count-only gcursor, single-wave shfl_up scan).
// ---------------------------------------------------------------------------
__global__ __launch_bounds__(512) void k_partition(const int* __restrict__ src,
                                                   const int* __restrict__ dst,
                                                   int* __restrict__ gcursor,
                                                   unsigned* __restrict__ part,
                                                   int E, int cap) {
  __shared__ int cnt[NB_P];
  __shared__ int lbase[NB_P];
  __shared__ int cur[NB_P];
  __shared__ int gbase[NB_P];
  __shared__ int ssum[512];
  __shared__ unsigned sval[PCHUNK];    // 16 KB
  __shared__ int sadr[PCHUNK];         // 16 KB
  const int t = threadIdx.x;
  const int base = blockIdx.x * PCHUNK;
  const int m = min(PCHUNK, E - base);
  for (int i = t; i < NB_P; i += 512) cnt[i] = 0;
  __syncthreads();
  int dl[8], sl[8];
#pragma unroll
  for (int u = 0; u < 8; ++u) {
    int i = t + 512 * u;
    dl[u] = -1;
    if (i < m) {
      dl[u] = dst[base + i];
      sl[u] = src[base + i];
      atomicAdd(&cnt[dl[u] >> BSHIFT], 1);
    }
  }
  __syncthreads();
  const int b2 = t * 2;
  int c0 = cnt[b2], c1 = cnt[b2 + 1];
  ssum[t] = c0 + c1;
  __syncthreads();
  if (t < 64) {
    int s[8];
    int tot = 0;
#pragma unroll
    for (int e = 0; e < 8; ++e) { s[e] = ssum[8 * t + e]; tot += s[e]; }
    int inc = tot;
#pragma unroll
    for (int o = 1; o < 64; o <<= 1) {
      int a = __shfl_up(inc, o);
      if (t >= o) inc += a;
    }
    int excl = inc - tot;
#pragma unroll
    for (int e = 0; e < 8; ++e) { ssum[8 * t + e] = excl; excl += s[e]; }
  }
  __syncthreads();
  int run = ssum[t];
  lbase[b2] = run; cur[b2] = run; run += c0;
  lbase[b2 + 1] = run; cur[b2 + 1] = run;
  __syncthreads();
  for (int i = t; i < NB_P; i += 512)
    gbase[i] = cnt[i] ? (i * cap + atomicAdd(&gcursor[i], cnt[i])) : 0;
  __syncthreads();
#pragma unroll
  for (int u = 0; u < 8; ++u) {
    if (dl[u] >= 0) {
      int b = dl[u] >> BSHIFT;
      int p = atomicAdd(&cur[b], 1);
      sval[p] = ((unsigned)sl[u] << BSHIFT) | (unsigned)(dl[u] & (BW - 1));
      sadr[p] = gbase[b] + (p - lbase[b]);
    }
  }
  __syncthreads();
  for (int i = t; i < m; i += 512) part[sadr[i]] = sval[i];
}

// ---------------------------------------------------------------------------
// D: sorted owner-exclusive aggregation (R13 structure). R14: gather reads
//    fp16 rows (uint2 = 4 halves per lane, 64 B/row) — traffic halved;
//    accumulation stays fp32. Mask/clamp scheme unchanged.
// ---------------------------------------------------------------------------
__global__ __launch_bounds__(512, 4) void k_agg(const __half* __restrict__ xh,
                                                const unsigned* __restrict__ part,
                                                const int* __restrict__ gcursor,
                                                float* __restrict__ agg, int n,
                                                int cap) {
  __shared__ float sacc[BW * IN_CH];   // 16 KB, owner-exclusive RMW
  __shared__ int sdeg[BW];
  __shared__ int hcnt[BW];
  __shared__ int boff[BW + 1];
  __shared__ int cur[BW];
  __shared__ unsigned sval[ACH];       // 16 KB sorted chunk
  const int t = threadIdx.x;
  const int sub = t >> 5;   // 16 subgroups of 32 lanes
  const int k = t & 31;     // lane within subgroup
#pragma unroll
  for (int i = 0; i < 8; ++i) sacc[t + 512 * i] = 0.0f;
  if (t < BW) sdeg[t] = 0;
  __syncthreads();
  const int b = blockIdx.x;
  const int e0 = b * cap;
  const int cn = gcursor[b];

  const uint2* __restrict__ xh2 = reinterpret_cast<const uint2*>(xh);
  const int eg = k >> 3;   // edge slot 0..3
  const int c4 = k & 7;    // 4-half channel group 0..7

  for (int base = 0; base < cn; base += ACH) {
    const int m = min(ACH, cn - base);
    if (t < BW) hcnt[t] = 0;
    __syncthreads();
    unsigned ev[8];
#pragma unroll
    for (int u = 0; u < 8; ++u) {
      int i = t + 512 * u;
      ev[u] = 0xFFFFFFFFu;
      if (i < m) {
        ev[u] = part[e0 + base + i];
        atomicAdd(&hcnt[ev[u] & (BW - 1)], 1);
      }
    }
    __syncthreads();
    // single-wave inclusive scan over 128 bins (2 bins/lane, no barriers)
    if (t < 64) {
      int v0 = hcnt[2 * t], v1 = hcnt[2 * t + 1];
      int s = v0 + v1;
#pragma unroll
      for (int o = 1; o < 64; o <<= 1) {
        int a = __shfl_up(s, o);
        if (t >= o) s += a;
      }
      int excl = s - v0 - v1;           // exclusive prefix of bin 2t
      boff[2 * t] = excl;
      cur[2 * t] = excl;
      boff[2 * t + 1] = excl + v0;
      cur[2 * t + 1] = excl + v0;
      sdeg[2 * t] += v0;
      sdeg[2 * t + 1] += v1;
      if (t == 0) boff[BW] = m;
    }
    __syncthreads();
#pragma unroll
    for (int u = 0; u < 8; ++u) {
      if (ev[u] != 0xFFFFFFFFu) {
        int dl = ev[u] & (BW - 1);
        int p = atomicAdd(&cur[dl], 1);
        sval[p] = ev[u];
      }
    }
    __syncthreads();
    // owner-exclusive segmented reduction: subgroup sub owns bins [8s, 8s+8)
    for (int dd = 0; dd < 8; ++dd) {
      const int d = (sub << 3) + dd;
      int j = boff[d];
      const int je = boff[d + 1];
      float ax = 0.f, ay = 0.f, az = 0.f, aw = 0.f;
      const int je1 = je - 1;
      for (; j < je; j += 16) {
        const int i0 = j + eg;
        const int i1 = j + 4 + eg;
        const int i2 = j + 8 + eg;
        const int i3 = j + 12 + eg;
        const float m0 = (i0 < je) ? 1.f : 0.f;
        const float m1 = (i1 < je) ? 1.f : 0.f;
        const float m2 = (i2 < je) ? 1.f : 0.f;
        const float m3 = (i3 < je) ? 1.f : 0.f;
        uint2 r0 = xh2[(int)(sval[min(i0, je1)] >> BSHIFT) * 8 + c4];
        uint2 r1 = xh2[(int)(sval[min(i1, je1)] >> BSHIFT) * 8 + c4];
        uint2 r2 = xh2[(int)(sval[min(i2, je1)] >> BSHIFT) * 8 + c4];
        uint2 r3 = xh2[(int)(sval[min(i3, je1)] >> BSHIFT) * 8 + c4];
        float2 p0a = __half22float2(*reinterpret_cast<__half2*>(&r0.x));
        float2 p0b = __half22float2(*reinterpret_cast<__half2*>(&r0.y));
        float2 p1a = __half22float2(*reinterpret_cast<__half2*>(&r1.x));
        float2 p1b = __half22float2(*reinterpret_cast<__half2*>(&r1.y));
        float2 p2a = __half22float2(*reinterpret_cast<__half2*>(&r2.x));
        float2 p2b = __half22float2(*reinterpret_cast<__half2*>(&r2.y));
        float2 p3a = __half22float2(*reinterpret_cast<__half2*>(&r3.x));
        float2 p3b = __half22float2(*reinterpret_cast<__half2*>(&r3.y));
        ax += m0 * p0a.x + m1 * p1a.x + m2 * p2a.x + m3 * p3a.x;
        ay += m0 * p0a.y + m1 * p1a.y + m2 * p2a.y + m3 * p3a.y;
        az += m0 * p0b.x + m1 * p1b.x + m2 * p2b.x + m3 * p3b.x;
        aw += m0 * p0b.y + m1 * p1b.y + m2 * p2b.y + m3 * p3b.y;
      }
      // reduce over the 4 edge slots (lane xor 8, 16 stays in subgroup)
      ax += __shfl_xor(ax, 8);  ax += __shfl_xor(ax, 16);
      ay += __shfl_xor(ay, 8);  ay += __shfl_xor(ay, 16);
      az += __shfl_xor(az, 8);  az += __shfl_xor(az, 16);
      aw += __shfl_xor(aw, 8);  aw += __shfl_xor(aw, 16);
      if (k < 8) {
        float4* sp = reinterpret_cast<float4*>(&sacc[d * IN_CH + 4 * k]);
        float4 s = *sp;
        s.x += ax; s.y += ay; s.z += az; s.w += aw;
        *sp = s;                         // owner-exclusive, plain RMW
      }
    }
    __syncthreads();
  }
  // write mean rows: subgroup sub writes its 8 owned nodes, coalesced 128B
  const int node0 = b << BSHIFT;
  for (int dd = 0; dd < 8; ++dd) {
    const int d = (sub << 3) + dd;
    const int node = node0 + d;
    if (node < n)
      agg[(size_t)node * IN_CH + k] =
          sacc[d * IN_CH + k] / fmaxf((float)sdeg[d], 1.0f);
  }
}

// ---------------------------------------------------------------------------
// E: register-tiled fp32 GEMM:  out = [x | agg] @ [Wr ; Wl]^T + b
//    (R1-proven: 56 VGPR, no spill; lin_r path keeps full-precision x)
// ---------------------------------------------------------------------------
#define VS_LD 68

__global__ __launch_bounds__(256) void k_out(const float* __restrict__ x,
                                             const float* __restrict__ agg,
                                             const float* __restrict__ Wl,
                                             const float* __restrict__ Wr,
                                             const float* __restrict__ bl,
                                             float* __restrict__ out, int n) {
  __shared__ float ws[64 * 128];    // ws[k][c]: k<32 -> Wr[c][k], k>=32 -> Wl[c][k-32]
  __shared__ float vs[64 * VS_LD];  // vs[k][m]: k<32 -> x[node0+m][k], k>=32 -> agg[...]
  const int t = threadIdx.x;
  const int node0 = blockIdx.x << 6;

  const float4* wr4 = reinterpret_cast<const float4*>(Wr);
  const float4* wl4 = reinterpret_cast<const float4*>(Wl);
#pragma unroll
  for (int r = 0; r < 4; ++r) {
    int i = t + 256 * r;            // [0,1024): c = i>>3, k0 = (i&7)*4
    int c = i >> 3;
    int k0 = (i & 7) << 2;
    float4 a = wr4[i];
    float4 b = wl4[i];
    ws[(k0 + 0) * 128 + c] = a.x;
    ws[(k0 + 1) * 128 + c] = a.y;
    ws[(k0 + 2) * 128 + c] = a.z;
    ws[(k0 + 3) * 128 + c] = a.w;
    ws[(32 + k0 + 0) * 128 + c] = b.x;
    ws[(32 + k0 + 1) * 128 + c] = b.y;
    ws[(32 + k0 + 2) * 128 + c] = b.z;
    ws[(32 + k0 + 3) * 128 + c] = b.w;
  }

#pragma unroll
  for (int r = 0; r < 2; ++r) {
    int i = t + 256 * r;            // [0,512): m = i>>3, q = i&7
    int m = i >> 3;
    int q = i & 7;
    int k0 = q << 2;
    int node = node0 + m;
    float4 a = make_float4(0.f, 0.f, 0.f, 0.f);
    float4 b = make_float4(0.f, 0.f, 0.f, 0.f);
    if (node < n) {
      a = reinterpret_cast<const float4*>(x + (size_t)node * IN_CH)[q];
      b = reinterpret_cast<const float4*>(agg + (size_t)node * IN_CH)[q];
    }
    vs[(k0 + 0) * VS_LD + m] = a.x;
    vs[(k0 + 1) * VS_LD + m] = a.y;
    vs[(k0 + 2) * VS_LD + m] = a.z;
    vs[(k0 + 3) * VS_LD + m] = a.w;
    vs[(32 + k0 + 0) * VS_LD + m] = b.x;
    vs[(32 + k0 + 1) * VS_LD + m] = b.y;
    vs[(32 + k0 + 2) * VS_LD + m] = b.z;
    vs[(32 + k0 + 3) * VS_LD + m] = b.w;
  }

  const int c0 = (t & 31) << 2;     // 32 channel-groups of 4
  const int m0 = (t >> 5) << 3;     // 8 node-groups of 8
  const float4 bias = *reinterpret_cast<const float4*>(bl + c0);

  __syncthreads();

  float acc[8][4];
#pragma unroll
  for (int i = 0; i < 8; ++i)
#pragma unroll
    for (int j = 0; j < 4; ++j) acc[i][j] = 0.0f;

#pragma unroll 8
  for (int k = 0; k < 64; ++k) {
    float4 w  = *reinterpret_cast<const float4*>(&ws[k * 128 + c0]);
    float4 a0 = *reinterpret_cast<const float4*>(&vs[k * VS_LD + m0]);
    float4 a1 = *reinterpret_cast<const float4*>(&vs[k * VS_LD + m0 + 4]);
    float av[8] = {a0.x, a0.y, a0.z, a0.w, a1.x, a1.y, a1.z, a1.w};
#pragma unroll
    for (int i = 0; i < 8; ++i) {
      acc[i][0] += av[i] * w.x;
      acc[i][1] += av[i] * w.y;
      acc[i][2] += av[i] * w.z;
      acc[i][3] += av[i] * w.w;
    }
  }

#pragma unroll
  for (int i = 0; i < 8; ++i) {
    int node = node0 + m0 + i;
    if (node < n) {
      float4 o;
      o.x = acc[i][0] + bias.x;
      o.y = acc[i][1] + bias.y;
      o.z = acc[i][2] + bias.z;
      o.w = acc[i][3] + bias.w;
      *reinterpret_cast<float4*>(out + (size_t)node * OUT_CH + c0) = o;
    }
  }
}

extern "C" void kernel_launch(void* const* d_in, const int* in_sizes, int n_in,
                              void* d_out, int out_size, void* d_ws, size_t ws_size,
                              hipStream_t stream) {
  const float* x  = (const float*)d_in[0];
  const int*   ei = (const int*)d_in[1];   // [2, E] row-major int32
  const float* Wl = (const float*)d_in[2];
  const float* Wr = (const float*)d_in[3];
  const float* bl = (const float*)d_in[4];
  float* out = (float*)d_out;

  const int n_nodes = in_sizes[0] / IN_CH;
  const int n_edges = in_sizes[1] / 2;
  const int* src = ei;
  const int* dst = ei + n_edges;
  const int NB = (n_nodes + BW - 1) >> BSHIFT;   // 782

  // fixed-capacity slab per bucket: >= 2x the mean bucket load, pow2, min 4096
  int cap = 4096;
  const int mean2 = (int)(2 * ((long long)n_edges / (NB > 0 ? NB : 1)));
  while (cap < mean2) cap <<= 1;

  char* ws = (char*)d_ws;
  auto align16 = [](size_t v) { return (v + 15) & ~(size_t)15; };
  int* gcursor   = (int*)ws;       ws += align16(NB_P * 4);
  unsigned* part = (unsigned*)ws;  ws += align16((size_t)NB_P * cap * 4);
  float* agg     = (float*)ws;     ws += align16((size_t)n_nodes * IN_CH * 4);
  __half* xh     = (__half*)ws;    ws += align16((size_t)n_nodes * IN_CH * 2);

  hipMemsetAsync(gcursor, 0, NB_P * sizeof(int), stream);

  const int total4 = n_nodes * IN_CH / 4;
  k_half<<<(total4 + 511) / 512, 512, 0, stream>>>(x, xh, total4);
  k_partition<<<(n_edges + PCHUNK - 1) / PCHUNK, 512, 0, stream>>>(
      src, dst, gcursor, part, n_edges, cap);
  k_agg<<<NB, 512, 0, stream>>>(xh, part, gcursor, agg, n_nodes, cap);

  const int nblk_out = (n_nodes + 63) >> 6;      // 64-node tiles
  k_out<<<nblk_out, 256, 0, stream>>>(x, agg, Wl, Wr, bl, out, n_nodes);
}

// Round 15
// 91.309 us; speedup vs baseline: 1.0078x; 1.0078x over previous
//
#include <hip/hip_runtime.h>

#define IN_CH 32
#define OUT_CH 128
#define BSHIFT 7
#define BW 128          // nodes per bucket
#define NB_P 1024       // >= ceil(100000/128)=782
#define PCHUNK 4096     // edges per partition block (512 thr x 8)
#define ACH 4096        // edges per k_agg sort-chunk (== slab cap: single pass)

// ---------------------------------------------------------------------------
// C: partition with LDS reorder (R13-proven: 512 thr / 4096-edge chunks,
//    count-only gcursor, single-wave shfl_up scan).
// ---------------------------------------------------------------------------
__global__ __launch_bounds__(512) void k_partition(const int* __restrict__ src,
                                                   const int* __restrict__ dst,
                                                   int* __restrict__ gcursor,
                                                   unsigned* __restrict__ part,
                                                   int E, int cap) {
  __shared__ int cnt[NB_P];
  __shared__ int lbase[NB_P];
  __shared__ int cur[NB_P];
  __shared__ int gbase[NB_P];
  __shared__ int ssum[512];
  __shared__ unsigned sval[PCHUNK];    // 16 KB
  __shared__ int sadr[PCHUNK];         // 16 KB
  const int t = threadIdx.x;
  const int base = blockIdx.x * PCHUNK;
  const int m = min(PCHUNK, E - base);
  for (int i = t; i < NB_P; i += 512) cnt[i] = 0;
  __syncthreads();
  int dl[8], sl[8];
#pragma unroll
  for (int u = 0; u < 8; ++u) {
    int i = t + 512 * u;
    dl[u] = -1;
    if (i < m) {
      dl[u] = dst[base + i];
      sl[u] = src[base + i];
      atomicAdd(&cnt[dl[u] >> BSHIFT], 1);
    }
  }
  __syncthreads();
  const int b2 = t * 2;
  int c0 = cnt[b2], c1 = cnt[b2 + 1];
  ssum[t] = c0 + c1;
  __syncthreads();
  // single-wave exclusive scan of the 512 per-thread sums (8 entries/lane)
  if (t < 64) {
    int s[8];
    int tot = 0;
#pragma unroll
    for (int e = 0; e < 8; ++e) { s[e] = ssum[8 * t + e]; tot += s[e]; }
    int inc = tot;
#pragma unroll
    for (int o = 1; o < 64; o <<= 1) {
      int a = __shfl_up(inc, o);
      if (t >= o) inc += a;
    }
    int excl = inc - tot;
#pragma unroll
    for (int e = 0; e < 8; ++e) { ssum[8 * t + e] = excl; excl += s[e]; }
  }
  __syncthreads();
  int run = ssum[t];
  lbase[b2] = run; cur[b2] = run; run += c0;
  lbase[b2 + 1] = run; cur[b2 + 1] = run;
  __syncthreads();
  for (int i = t; i < NB_P; i += 512)
    gbase[i] = cnt[i] ? (i * cap + atomicAdd(&gcursor[i], cnt[i])) : 0;
  __syncthreads();
#pragma unroll
  for (int u = 0; u < 8; ++u) {
    if (dl[u] >= 0) {
      int b = dl[u] >> BSHIFT;
      int p = atomicAdd(&cur[b], 1);
      sval[p] = ((unsigned)sl[u] << BSHIFT) | (unsigned)(dl[u] & (BW - 1));
      sadr[p] = gbase[b] + (p - lbase[b]);
    }
  }
  __syncthreads();
  for (int i = t; i < m; i += 512) part[sadr[i]] = sval[i];
}

// ---------------------------------------------------------------------------
// D: sorted owner-exclusive aggregation (R13-proven; fp32 gather — fp16 was
//    proven transaction-neutral in R14: one 128B line per edge either way).
// ---------------------------------------------------------------------------
__global__ __launch_bounds__(512, 4) void k_agg(const float* __restrict__ x,
                                                const unsigned* __restrict__ part,
                                                const int* __restrict__ gcursor,
                                                float* __restrict__ agg, int n,
                                                int cap) {
  __shared__ float sacc[BW * IN_CH];   // 16 KB, owner-exclusive RMW
  __shared__ int sdeg[BW];
  __shared__ int hcnt[BW];
  __shared__ int boff[BW + 1];
  __shared__ int cur[BW];
  __shared__ unsigned sval[ACH];       // 16 KB sorted chunk
  const int t = threadIdx.x;
  const int sub = t >> 5;   // 16 subgroups of 32 lanes
  const int k = t & 31;     // lane within subgroup
#pragma unroll
  for (int i = 0; i < 8; ++i) sacc[t + 512 * i] = 0.0f;
  if (t < BW) sdeg[t] = 0;
  __syncthreads();
  const int b = blockIdx.x;
  const int e0 = b * cap;
  const int cn = gcursor[b];

  const float4* __restrict__ x4 = reinterpret_cast<const float4*>(x);
  const int eg = k >> 3;   // edge slot 0..3
  const int c4 = k & 7;    // float4 channel group 0..7

  for (int base = 0; base < cn; base += ACH) {
    const int m = min(ACH, cn - base);
    if (t < BW) hcnt[t] = 0;
    __syncthreads();
    unsigned ev[8];
#pragma unroll
    for (int u = 0; u < 8; ++u) {
      int i = t + 512 * u;
      ev[u] = 0xFFFFFFFFu;
      if (i < m) {
        ev[u] = part[e0 + base + i];
        atomicAdd(&hcnt[ev[u] & (BW - 1)], 1);
      }
    }
    __syncthreads();
    // single-wave inclusive scan over 128 bins (2 bins/lane, no barriers)
    if (t < 64) {
      int v0 = hcnt[2 * t], v1 = hcnt[2 * t + 1];
      int s = v0 + v1;
#pragma unroll
      for (int o = 1; o < 64; o <<= 1) {
        int a = __shfl_up(s, o);
        if (t >= o) s += a;
      }
      int excl = s - v0 - v1;           // exclusive prefix of bin 2t
      boff[2 * t] = excl;
      cur[2 * t] = excl;
      boff[2 * t + 1] = excl + v0;
      cur[2 * t + 1] = excl + v0;
      sdeg[2 * t] += v0;
      sdeg[2 * t + 1] += v1;
      if (t == 0) boff[BW] = m;
    }
    __syncthreads();
#pragma unroll
    for (int u = 0; u < 8; ++u) {
      if (ev[u] != 0xFFFFFFFFu) {
        int dl = ev[u] & (BW - 1);
        int p = atomicAdd(&cur[dl], 1);
        sval[p] = ev[u];
      }
    }
    __syncthreads();
    // owner-exclusive segmented reduction: subgroup sub owns bins [8s, 8s+8)
    for (int dd = 0; dd < 8; ++dd) {
      const int d = (sub << 3) + dd;
      int j = boff[d];
      const int je = boff[d + 1];
      float ax = 0.f, ay = 0.f, az = 0.f, aw = 0.f;
      const int je1 = je - 1;
      for (; j < je; j += 16) {
        const int i0 = j + eg;
        const int i1 = j + 4 + eg;
        const int i2 = j + 8 + eg;
        const int i3 = j + 12 + eg;
        const float m0 = (i0 < je) ? 1.f : 0.f;
        const float m1 = (i1 < je) ? 1.f : 0.f;
        const float m2 = (i2 < je) ? 1.f : 0.f;
        const float m3 = (i3 < je) ? 1.f : 0.f;
        float4 v0 = x4[(int)(sval[min(i0, je1)] >> BSHIFT) * 8 + c4];
        float4 v1 = x4[(int)(sval[min(i1, je1)] >> BSHIFT) * 8 + c4];
        float4 v2 = x4[(int)(sval[min(i2, je1)] >> BSHIFT) * 8 + c4];
        float4 v3 = x4[(int)(sval[min(i3, je1)] >> BSHIFT) * 8 + c4];
        ax += m0 * v0.x + m1 * v1.x + m2 * v2.x + m3 * v3.x;
        ay += m0 * v0.y + m1 * v1.y + m2 * v2.y + m3 * v3.y;
        az += m0 * v0.z + m1 * v1.z + m2 * v2.z + m3 * v3.z;
        aw += m0 * v0.w + m1 * v1.w + m2 * v2.w + m3 * v3.w;
      }
      // reduce over the 4 edge slots (lane xor 8, 16 stays in subgroup)
      ax += __shfl_xor(ax, 8);  ax += __shfl_xor(ax, 16);
      ay += __shfl_xor(ay, 8);  ay += __shfl_xor(ay, 16);
      az += __shfl_xor(az, 8);  az += __shfl_xor(az, 16);
      aw += __shfl_xor(aw, 8);  aw += __shfl_xor(aw, 16);
      if (k < 8) {
        float4* sp = reinterpret_cast<float4*>(&sacc[d * IN_CH + 4 * k]);
        float4 s = *sp;
        s.x += ax; s.y += ay; s.z += az; s.w += aw;
        *sp = s;                         // owner-exclusive, plain RMW
      }
    }
    __syncthreads();
  }
  // write mean rows: subgroup sub writes its 8 owned nodes, coalesced 128B
  const int node0 = b << BSHIFT;
  for (int dd = 0; dd < 8; ++dd) {
    const int d = (sub << 3) + dd;
    const int node = node0 + d;
    if (node < n)
      agg[(size_t)node * IN_CH + k] =
          sacc[d * IN_CH + k] / fmaxf((float)sdeg[d], 1.0f);
  }
}

// ---------------------------------------------------------------------------
// E: register-tiled fp32 GEMM:  out = [x | agg] @ [Wr ; Wl]^T + b
//    (R1-proven: 56 VGPR, no spill, ~15 us)
// ---------------------------------------------------------------------------
#define VS_LD 68

__global__ __launch_bounds__(256) void k_out(const float* __restrict__ x,
                                             const float* __restrict__ agg,
                                             const float* __restrict__ Wl,
                                             const float* __restrict__ Wr,
                                             const float* __restrict__ bl,
                                             float* __restrict__ out, int n) {
  __shared__ float ws[64 * 128];    // ws[k][c]: k<32 -> Wr[c][k], k>=32 -> Wl[c][k-32]
  __shared__ float vs[64 * VS_LD];  // vs[k][m]: k<32 -> x[node0+m][k], k>=32 -> agg[...]
  const int t = threadIdx.x;
  const int node0 = blockIdx.x << 6;

  const float4* wr4 = reinterpret_cast<const float4*>(Wr);
  const float4* wl4 = reinterpret_cast<const float4*>(Wl);
#pragma unroll
  for (int r = 0; r < 4; ++r) {
    int i = t + 256 * r;            // [0,1024): c = i>>3, k0 = (i&7)*4
    int c = i >> 3;
    int k0 = (i & 7) << 2;
    float4 a = wr4[i];
    float4 b = wl4[i];
    ws[(k0 + 0) * 128 + c] = a.x;
    ws[(k0 + 1) * 128 + c] = a.y;
    ws[(k0 + 2) * 128 + c] = a.z;
    ws[(k0 + 3) * 128 + c] = a.w;
    ws[(32 + k0 + 0) * 128 + c] = b.x;
    ws[(32 + k0 + 1) * 128 + c] = b.y;
    ws[(32 + k0 + 2) * 128 + c] = b.z;
    ws[(32 + k0 + 3) * 128 + c] = b.w;
  }

#pragma unroll
  for (int r = 0; r < 2; ++r) {
    int i = t + 256 * r;            // [0,512): m = i>>3, q = i&7
    int m = i >> 3;
    int q = i & 7;
    int k0 = q << 2;
    int node = node0 + m;
    float4 a = make_float4(0.f, 0.f, 0.f, 0.f);
    float4 b = make_float4(0.f, 0.f, 0.f, 0.f);
    if (node < n) {
      a = reinterpret_cast<const float4*>(x + (size_t)node * IN_CH)[q];
      b = reinterpret_cast<const float4*>(agg + (size_t)node * IN_CH)[q];
    }
    vs[(k0 + 0) * VS_LD + m] = a.x;
    vs[(k0 + 1) * VS_LD + m] = a.y;
    vs[(k0 + 2) * VS_LD + m] = a.z;
    vs[(k0 + 3) * VS_LD + m] = a.w;
    vs[(32 + k0 + 0) * VS_LD + m] = b.x;
    vs[(32 + k0 + 1) * VS_LD + m] = b.y;
    vs[(32 + k0 + 2) * VS_LD + m] = b.z;
    vs[(32 + k0 + 3) * VS_LD + m] = b.w;
  }

  const int c0 = (t & 31) << 2;     // 32 channel-groups of 4
  const int m0 = (t >> 5) << 3;     // 8 node-groups of 8
  const float4 bias = *reinterpret_cast<const float4*>(bl + c0);

  __syncthreads();

  float acc[8][4];
#pragma unroll
  for (int i = 0; i < 8; ++i)
#pragma unroll
    for (int j = 0; j < 4; ++j) acc[i][j] = 0.0f;

#pragma unroll 8
  for (int k = 0; k < 64; ++k) {
    float4 w  = *reinterpret_cast<const float4*>(&ws[k * 128 + c0]);
    float4 a0 = *reinterpret_cast<const float4*>(&vs[k * VS_LD + m0]);
    float4 a1 = *reinterpret_cast<const float4*>(&vs[k * VS_LD + m0 + 4]);
    float av[8] = {a0.x, a0.y, a0.z, a0.w, a1.x, a1.y, a1.z, a1.w};
#pragma unroll
    for (int i = 0; i < 8; ++i) {
      acc[i][0] += av[i] * w.x;
      acc[i][1] += av[i] * w.y;
      acc[i][2] += av[i] * w.z;
      acc[i][3] += av[i] * w.w;
    }
  }

#pragma unroll
  for (int i = 0; i < 8; ++i) {
    int node = node0 + m0 + i;
    if (node < n) {
      float4 o;
      o.x = acc[i][0] + bias.x;
      o.y = acc[i][1] + bias.y;
      o.z = acc[i][2] + bias.z;
      o.w = acc[i][3] + bias.w;
      *reinterpret_cast<float4*>(out + (size_t)node * OUT_CH + c0) = o;
    }
  }
}

extern "C" void kernel_launch(void* const* d_in, const int* in_sizes, int n_in,
                              void* d_out, int out_size, void* d_ws, size_t ws_size,
                              hipStream_t stream) {
  const float* x  = (const float*)d_in[0];
  const int*   ei = (const int*)d_in[1];   // [2, E] row-major int32
  const float* Wl = (const float*)d_in[2];
  const float* Wr = (const float*)d_in[3];
  const float* bl = (const float*)d_in[4];
  float* out = (float*)d_out;

  const int n_nodes = in_sizes[0] / IN_CH;
  const int n_edges = in_sizes[1] / 2;
  const int* src = ei;
  const int* dst = ei + n_edges;
  const int NB = (n_nodes + BW - 1) >> BSHIFT;   // 782

  // fixed-capacity slab per bucket: >= 2x the mean bucket load, pow2, min 4096
  int cap = 4096;
  const int mean2 = (int)(2 * ((long long)n_edges / (NB > 0 ? NB : 1)));
  while (cap < mean2) cap <<= 1;

  char* ws = (char*)d_ws;
  auto align16 = [](size_t v) { return (v + 15) & ~(size_t)15; };
  int* gcursor   = (int*)ws;       ws += align16(NB_P * 4);
  unsigned* part = (unsigned*)ws;  ws += align16((size_t)NB_P * cap * 4);
  float* agg     = (float*)ws;     ws += align16((size_t)n_nodes * IN_CH * 4);

  hipMemsetAsync(gcursor, 0, NB_P * sizeof(int), stream);

  k_partition<<<(n_edges + PCHUNK - 1) / PCHUNK, 512, 0, stream>>>(
      src, dst, gcursor, part, n_edges, cap);
  k_agg<<<NB, 512, 0, stream>>>(x, part, gcursor, agg, n_nodes, cap);

  const int nblk_out = (n_nodes + 63) >> 6;      // 64-node tiles
  k_out<<<nblk_out, 256, 0, stream>>>(x, agg, Wl, Wr, bl, out, n_nodes);
}